// Round 1
// baseline (860.778 us; speedup 1.0000x reference)
//
#include <hip/hip_runtime.h>
#include <hip/hip_bf16.h>

// Problem constants (from reference): N=16384, C=10000, D=128, LR=0.5
#define N_SAMPLES 16384
#define N_CLASSES 10000
#define DIM 128
#define LR_CONST 0.5f

// Fused kernel: one block per sample.
//  Phase 1: scan labels[n, :] (one-hot) with float4 loads to find class c.
//  Phase 2: diff = center[c,:] - preds[n,:]; atomicAdd into grad[c,:]; bump counts[c].
__global__ __launch_bounds__(256) void gather_scatter_kernel(
    const float* __restrict__ labels,   // [N, C]
    const float* __restrict__ preds,    // [N, D]
    const float* __restrict__ center,   // [C, D]
    float* __restrict__ grad,           // [C, D] (pre-zeroed)
    int* __restrict__ counts)           // [C]    (pre-zeroed)
{
    const int n = blockIdx.x;
    __shared__ int s_class;

    // ---- Phase 1: find the one-hot column ----
    const float4* row = reinterpret_cast<const float4*>(labels + (size_t)n * N_CLASSES);
    const int nvec = N_CLASSES / 4;  // 2500, exact
    for (int j = threadIdx.x; j < nvec; j += blockDim.x) {
        float4 v = row[j];
        int c = -1;
        if (v.x > 0.5f)      c = 4 * j + 0;
        else if (v.y > 0.5f) c = 4 * j + 1;
        else if (v.z > 0.5f) c = 4 * j + 2;
        else if (v.w > 0.5f) c = 4 * j + 3;
        if (c >= 0) s_class = c;  // exactly one thread in the block hits this
    }
    __syncthreads();
    const int c = s_class;

    // ---- Phase 2: diff + scatter ----
    if (threadIdx.x == 0) {
        atomicAdd(&counts[c], 1);
    }
    if (threadIdx.x < DIM) {
        const int d = threadIdx.x;
        float diff = center[(size_t)c * DIM + d] - preds[(size_t)n * DIM + d];
        atomicAdd(&grad[(size_t)c * DIM + d], diff);
    }
}

// Finalize: out[c,d] = center[c,d] - LR * grad[c,d] / (counts[c] + 1)
__global__ __launch_bounds__(256) void finalize_kernel(
    const float* __restrict__ center,
    const float* __restrict__ grad,
    const int* __restrict__ counts,
    float* __restrict__ out)
{
    int t = blockIdx.x * blockDim.x + threadIdx.x;
    if (t >= N_CLASSES * DIM) return;
    int c = t >> 7;  // / DIM
    float cnt = (float)counts[c] + 1.0f;
    out[t] = center[t] - LR_CONST * (grad[t] / cnt);
}

extern "C" void kernel_launch(void* const* d_in, const int* in_sizes, int n_in,
                              void* d_out, int out_size, void* d_ws, size_t ws_size,
                              hipStream_t stream) {
    const float* preds  = (const float*)d_in[0];  // [N, D]
    const float* labels = (const float*)d_in[1];  // [N, C]
    const float* center = (const float*)d_in[2];  // [C, D]
    float* out = (float*)d_out;                   // [C, D]

    // Workspace layout: grad [C*D] f32, then counts [C] int32
    float* grad  = (float*)d_ws;
    int*   counts = (int*)((char*)d_ws + (size_t)N_CLASSES * DIM * sizeof(float));
    size_t zero_bytes = (size_t)N_CLASSES * DIM * sizeof(float) + (size_t)N_CLASSES * sizeof(int);

    // Zero grad + counts (ws is re-poisoned to 0xAA before every launch).
    hipMemsetAsync(d_ws, 0, zero_bytes, stream);

    gather_scatter_kernel<<<N_SAMPLES, 256, 0, stream>>>(labels, preds, center, grad, counts);

    const int total = N_CLASSES * DIM;
    finalize_kernel<<<(total + 255) / 256, 256, 0, stream>>>(center, grad, counts, out);
}

// Round 2
// 770.413 us; speedup vs baseline: 1.1173x; 1.1173x over previous
//
#include <hip/hip_runtime.h>
#include <hip/hip_bf16.h>

// Problem constants (from reference): N=16384, C=10000, D=128, LR=0.5
#define N_SAMPLES 16384
#define N_CLASSES 10000
#define DIM 128
#define LR_CONST 0.5f

typedef float f32x4 __attribute__((ext_vector_type(4)));

// One wave (64 lanes) per sample row. Scan labels[n,:] in 512-float chunks
// (2 x float4 per lane) with early exit once the one-hot 1.0 is found
// (one-hot => rest of row is guaranteed zero; expected ~52% of row read).
// Then scatter diff into grad via atomics (avg 1.6 samples/class -> negligible
// contention). No __syncthreads anywhere; 4 independent waves per block.
__global__ __launch_bounds__(256) void gather_scatter_kernel(
    const float* __restrict__ labels,   // [N, C]
    const float* __restrict__ preds,    // [N, D]
    const float* __restrict__ center,   // [C, D]
    float* __restrict__ grad,           // [C, D] (pre-zeroed)
    int* __restrict__ counts)           // [C]    (pre-zeroed)
{
    const int lane = threadIdx.x & 63;
    const int n = blockIdx.x * 4 + (threadIdx.x >> 6);  // 4096 blocks x 4 waves

    const f32x4* row = reinterpret_cast<const f32x4*>(labels + (size_t)n * N_CLASSES);
    const int nvec = N_CLASSES / 4;  // 2500 float4 per row

    int c = -1;
    for (int cb = 0; cb < nvec; cb += 128) {   // 128 float4 = 512 floats per wave-iter
        const int j0 = cb + lane;
        const int j1 = cb + 64 + lane;
        f32x4 v0 = (f32x4)(0.0f);
        f32x4 v1 = (f32x4)(0.0f);
        if (j0 < nvec) v0 = __builtin_nontemporal_load(row + j0);
        if (j1 < nvec) v1 = __builtin_nontemporal_load(row + j1);

        int local = -1;
        if      (v0.x > 0.5f) local = 4 * j0 + 0;
        else if (v0.y > 0.5f) local = 4 * j0 + 1;
        else if (v0.z > 0.5f) local = 4 * j0 + 2;
        else if (v0.w > 0.5f) local = 4 * j0 + 3;
        else if (v1.x > 0.5f) local = 4 * j1 + 0;
        else if (v1.y > 0.5f) local = 4 * j1 + 1;
        else if (v1.z > 0.5f) local = 4 * j1 + 2;
        else if (v1.w > 0.5f) local = 4 * j1 + 3;

        unsigned long long m = __ballot(local >= 0);
        if (m) {
            const int src = __ffsll((unsigned long long)m) - 1;
            c = __shfl(local, src);   // wave-uniform class index
            break;
        }
    }

    // ---- scatter: diff = center[c,:] - preds[n,:] into grad[c,:] ----
    if (lane == 0) atomicAdd(&counts[c], 1);
    const size_t cb128 = (size_t)c * DIM;
    const size_t nb128 = (size_t)n * DIM;
    const float d0 = center[cb128 + lane]      - preds[nb128 + lane];
    const float d1 = center[cb128 + lane + 64] - preds[nb128 + lane + 64];
    atomicAdd(&grad[cb128 + lane], d0);
    atomicAdd(&grad[cb128 + lane + 64], d1);
}

// Finalize: out[c,d] = center[c,d] - LR * grad[c,d] / (counts[c] + 1)
__global__ __launch_bounds__(256) void finalize_kernel(
    const float* __restrict__ center,
    const float* __restrict__ grad,
    const int* __restrict__ counts,
    float* __restrict__ out)
{
    int t = blockIdx.x * blockDim.x + threadIdx.x;
    if (t >= N_CLASSES * DIM) return;
    int c = t >> 7;  // / DIM
    float cnt = (float)counts[c] + 1.0f;
    float v = center[t] - LR_CONST * (grad[t] / cnt);
    __builtin_nontemporal_store(v, out + t);
}

extern "C" void kernel_launch(void* const* d_in, const int* in_sizes, int n_in,
                              void* d_out, int out_size, void* d_ws, size_t ws_size,
                              hipStream_t stream) {
    const float* preds  = (const float*)d_in[0];  // [N, D]
    const float* labels = (const float*)d_in[1];  // [N, C]
    const float* center = (const float*)d_in[2];  // [C, D]
    float* out = (float*)d_out;                   // [C, D]

    // Workspace layout: grad [C*D] f32, then counts [C] int32
    float* grad   = (float*)d_ws;
    int*   counts = (int*)((char*)d_ws + (size_t)N_CLASSES * DIM * sizeof(float));
    size_t zero_bytes = (size_t)N_CLASSES * DIM * sizeof(float) + (size_t)N_CLASSES * sizeof(int);

    // Zero grad + counts (ws is re-poisoned to 0xAA before every launch).
    hipMemsetAsync(d_ws, 0, zero_bytes, stream);

    gather_scatter_kernel<<<N_SAMPLES / 4, 256, 0, stream>>>(labels, preds, center, grad, counts);

    const int total = N_CLASSES * DIM;
    finalize_kernel<<<(total + 255) / 256, 256, 0, stream>>>(center, grad, counts, out);
}